// Round 6
// baseline (86.016 us; speedup 1.0000x reference)
//
#include <hip/hip_runtime.h>
#include <hip/hip_bf16.h>
#include <hip/hip_cooperative_groups.h>

namespace cg = cooperative_groups;

#define BATCH 8
#define SEQ   4096
#define DEG   16
#define FD    128
#define NTOT  (BATCH * SEQ)
#define ALPHA 0.2f
#define LDS_WK 132   // 128 bf16 + 4 pad per n-row (row stride 264 B)

typedef __attribute__((ext_vector_type(8))) short short8v;   // 8 bf16 (4 VGPRs)
typedef __attribute__((ext_vector_type(4))) short short4v;   // 4 bf16 (2 VGPRs)
typedef __attribute__((ext_vector_type(4))) float float4v;   // MFMA acc
typedef __attribute__((ext_vector_type(4))) float f32x4;
typedef __attribute__((ext_vector_type(2))) float f32x2;

__device__ __forceinline__ unsigned short f2bf(float f) {
    unsigned int u = __float_as_uint(f);
    u += 0x7fffu + ((u >> 16) & 1u);   // round-to-nearest-even
    return (unsigned short)(u >> 16);
}

// Fused cooperative kernel. Phase 1 == round-5 gat_proj (operand-swapped MFMA,
// fused s1/s2 dots). grid.sync(). Phase 2 == round-5 gat_aggr, 16 nodes/wave.
// 512 blocks, bid&7 == batch == XCD: all hb/s12 producer-consumer pairs are
// same-XCD, so phase-2 gathers hit the XCD-local L2 (no kernel-boundary flush).
__global__ __launch_bounds__(256, 2) void gat_fused(
    const float* __restrict__ x, const float* __restrict__ W,
    const float* __restrict__ avec, const int* __restrict__ adj,
    unsigned short* __restrict__ hb, float2* __restrict__ s12,
    float* __restrict__ out)
{
    __shared__ unsigned short Wt[128 * LDS_WK];   // W transposed: Wt[n][k], bf16

    const int t = threadIdx.x;
    const int bid = blockIdx.x;
    const int xcd = bid & 7, blk = bid >> 3;            // batch == XCD
    const int bBase = xcd * SEQ;
    const long long rowBase = (long long)bBase + (long long)blk * 64;

    // ======== PHASE 1: h = xW (bf16) + fused s1/s2 score dots ========

    // stage W -> LDS transposed (coalesced: each half-wave reads a 512-B row)
    {
        const int q = t & 31;                 // n-quad: n = 4q..4q+3
        const int kh = t >> 5;                // 0..7
        #pragma unroll
        for (int j = 0; j < 8; ++j) {
            const int kp = kh + 8 * j;        // k-pair, k = 2kp, 2kp+1
            const f32x4 w0 = *reinterpret_cast<const f32x4*>(&W[(2 * kp) * FD + 4 * q]);
            const f32x4 w1 = *reinterpret_cast<const f32x4*>(&W[(2 * kp + 1) * FD + 4 * q]);
            #pragma unroll
            for (int e2 = 0; e2 < 4; ++e2) {
                const unsigned int pk = (unsigned int)f2bf(w0[e2])
                                      | ((unsigned int)f2bf(w1[e2]) << 16);
                *reinterpret_cast<unsigned int*>(&Wt[(4 * q + e2) * LDS_WK + 2 * kp]) = pk;
            }
        }
    }

    // x rows global -> registers -> bf16 frags (B operand); nontemporal keeps L2 clean
    const int lane = t & 63, wv = t >> 6;
    const int g = lane >> 4, mrow = lane & 15;
    const long long node1 = rowBase + wv * 16 + mrow;   // this lane's node
    short8v xfrag[4];
    {
        const float* xr = x + node1 * FD + 4 * g;
        #pragma unroll
        for (int kb = 0; kb < 4; ++kb) {
            const f32x4 x0 = __builtin_nontemporal_load(
                reinterpret_cast<const f32x4*>(xr + 32 * kb));
            const f32x4 x1 = __builtin_nontemporal_load(
                reinterpret_cast<const f32x4*>(xr + 32 * kb + 16));
            short8v f;
            f[0] = (short)f2bf(x0[0]); f[1] = (short)f2bf(x0[1]);
            f[2] = (short)f2bf(x0[2]); f[3] = (short)f2bf(x0[3]);
            f[4] = (short)f2bf(x1[0]); f[5] = (short)f2bf(x1[1]);
            f[6] = (short)f2bf(x1[2]); f[7] = (short)f2bf(x1[3]);
            xfrag[kb] = f;
        }
    }
    __syncthreads();

    // MFMA main: 8 n-tiles x 4 k-steps, D = Wt-tile * x-tile (transposed product)
    float4v acc[8];
    #pragma unroll
    for (int tn = 0; tn < 8; ++tn) { acc[tn][0] = 0.f; acc[tn][1] = 0.f; acc[tn][2] = 0.f; acc[tn][3] = 0.f; }

    #pragma unroll
    for (int tn = 0; tn < 8; ++tn) {
        const int nbase = (16 * tn + mrow) * LDS_WK + 4 * g;
        #pragma unroll
        for (int kb = 0; kb < 4; ++kb) {
            const short4v lo = *reinterpret_cast<const short4v*>(&Wt[nbase + 32 * kb]);
            const short4v hi = *reinterpret_cast<const short4v*>(&Wt[nbase + 32 * kb + 16]);
            short8v wf;
            wf[0] = lo[0]; wf[1] = lo[1]; wf[2] = lo[2]; wf[3] = lo[3];
            wf[4] = hi[0]; wf[5] = hi[1]; wf[6] = hi[2]; wf[7] = hi[3];
            acc[tn] = __builtin_amdgcn_mfma_f32_16x16x32_bf16(wf, xfrag[kb], acc[tn], 0, 0, 0);
        }
    }

    // epilogue: lane owns node `node1`, h cols 16tn+4g+0..3 per tn
    float s1p = 0.f, s2p = 0.f;
    #pragma unroll
    for (int tn = 0; tn < 8; ++tn) {
        const int col = 16 * tn + 4 * g;
        const unsigned int u0 = (unsigned int)f2bf(acc[tn][0])
                              | ((unsigned int)f2bf(acc[tn][1]) << 16);
        const unsigned int u1 = (unsigned int)f2bf(acc[tn][2])
                              | ((unsigned int)f2bf(acc[tn][3]) << 16);
        *reinterpret_cast<uint2*>(&hb[node1 * FD + col]) = make_uint2(u0, u1);
        const f32x4 a1 = *reinterpret_cast<const f32x4*>(&avec[col]);
        const f32x4 a2 = *reinterpret_cast<const f32x4*>(&avec[FD + col]);
        #pragma unroll
        for (int r = 0; r < 4; ++r) {
            s1p = fmaf(acc[tn][r], a1[r], s1p);
            s2p = fmaf(acc[tn][r], a2[r], s2p);
        }
    }
    s1p += __shfl_xor(s1p, 16, 64);  s2p += __shfl_xor(s2p, 16, 64);
    s1p += __shfl_xor(s1p, 32, 64);  s2p += __shfl_xor(s2p, 32, 64);
    if (lane < 16)
        s12[rowBase + wv * 16 + lane] = make_float2(s1p, s2p);

    // ======== grid-wide barrier (no L2 flush: hb/s12 stay XCD-L2-resident) ========
    cg::this_grid().sync();

    // ======== PHASE 2: softmax + gather-aggregate, 16 nodes per wave ========
    const int wv_u = __builtin_amdgcn_readfirstlane(t) >> 6;  // uniform wave id
    const int c = lane & 15;
    const int nodeBase = bBase + blk * 64 + wv_u * 16;

    for (int j = 0; j < 16; ++j) {
        const int node = nodeBase + j;                        // uniform per wave
        const int* ap = adj + (long long)node * DEG;
        int nb[16];
        #pragma unroll
        for (int d = 0; d < 16; ++d) nb[d] = ap[d];           // SGPR (scalar loads)

        // lane-parallel softmax: lane c owns e_c (x4 dup across g-groups)
        const int nbc = ap[c];
        const float s2n0 = s12[bBase + nb[0]].y;              // scalar load
        float ev = s12[bBase + nbc].x + s2n0;
        ev = ev > 0.f ? ev : ALPHA * ev;
        float p = __expf(ev);          // no max-sub: |e| small, fp32 safe (validated)
        float sum = p;
        #pragma unroll
        for (int mo = 1; mo < 16; mo <<= 1) sum += __shfl_xor(sum, mo, 64);
        p *= 1.f / sum;                // lane c holds normalized attn p_c

        // gathers: lane owns h-dword `lane`; each load = one 256-B row, L2-hit
        float a0 = 0.f, a1 = 0.f;
        #pragma unroll
        for (int d = 0; d < 16; ++d) {
            const float pd = __uint_as_float(
                __builtin_amdgcn_readlane(__float_as_uint(p), d));  // SGPR broadcast
            const unsigned int* rp = reinterpret_cast<const unsigned int*>(
                hb + (((long long)(bBase + nb[d])) << 7));
            const unsigned int u = rp[lane];
            a0 = fmaf(pd, __uint_as_float(u << 16), a0);
            a1 = fmaf(pd, __uint_as_float(u & 0xffff0000u), a1);
        }

        f32x2 o;
        o[0] = a0 > 0.f ? a0 : (__expf(a0) - 1.f);
        o[1] = a1 > 0.f ? a1 : (__expf(a1) - 1.f);
        __builtin_nontemporal_store(o, reinterpret_cast<f32x2*>(
            out + (long long)node * FD + lane * 2));
    }
}

extern "C" void kernel_launch(void* const* d_in, const int* in_sizes, int n_in,
                              void* d_out, int out_size, void* d_ws, size_t ws_size,
                              hipStream_t stream) {
    const float* x  = (const float*)d_in[0];
    const int* adj  = (const int*)d_in[1];
    const float* W  = (const float*)d_in[2];
    const float* a  = (const float*)d_in[3];
    float* out = (float*)d_out;

    unsigned short* hb = (unsigned short*)d_ws;                          // 8 MB bf16 h
    float2* s12 = (float2*)((char*)d_ws + (size_t)NTOT * FD * 2);        // 256 KB scores

    void* args[] = {(void*)&x, (void*)&W, (void*)&a, (void*)&adj,
                    (void*)&hb, (void*)&s12, (void*)&out};
    hipLaunchCooperativeKernel((const void*)gat_fused, dim3(512), dim3(256),
                               args, 0, stream);
}

// Round 7
// 22.928 us; speedup vs baseline: 3.7515x; 3.7515x over previous
//
#include <hip/hip_runtime.h>
#include <hip/hip_bf16.h>

#define BATCH 8
#define SEQ   4096
#define DEG   16
#define FD    128
#define NTOT  (BATCH * SEQ)
#define ALPHA 0.2f
#define LDS_WK 132   // 128 bf16 + 4 pad per n-row (row stride 264 B)

typedef __attribute__((ext_vector_type(8))) short short8v;   // 8 bf16 (4 VGPRs)
typedef __attribute__((ext_vector_type(4))) short short4v;   // 4 bf16 (2 VGPRs)
typedef __attribute__((ext_vector_type(4))) float float4v;   // MFMA acc
typedef __attribute__((ext_vector_type(4))) float f32x4;
typedef __attribute__((ext_vector_type(2))) float f32x2;

__device__ __forceinline__ unsigned short f2bf(float f) {
    unsigned int u = __float_as_uint(f);
    u += 0x7fffu + ((u >> 16) & 1u);   // round-to-nearest-even
    return (unsigned short)(u >> 16);
}

// Kernel A (unchanged from round 5): transposed-product MFMA h^T = (xW)^T,
// fused s1/s2 dots, wide dwordx2 hb stores.
__global__ __launch_bounds__(256) void gat_proj(
    const float* __restrict__ x, const float* __restrict__ W,
    const float* __restrict__ avec, unsigned short* __restrict__ hb,
    float2* __restrict__ s12)
{
    __shared__ unsigned short Wt[128 * LDS_WK];   // W transposed: Wt[n][k], bf16

    const int t = threadIdx.x;
    const int bid = blockIdx.x;
    const int xcd = bid & 7, blk = bid >> 3;            // batch == XCD
    const long long rowBase = (long long)xcd * SEQ + (long long)blk * 64;

    // stage W -> LDS transposed (coalesced: each half-wave reads a 512-B row)
    {
        const int q = t & 31;                 // n-quad: n = 4q..4q+3
        const int kh = t >> 5;                // 0..7
        #pragma unroll
        for (int j = 0; j < 8; ++j) {
            const int kp = kh + 8 * j;        // k-pair, k = 2kp, 2kp+1
            const f32x4 w0 = *reinterpret_cast<const f32x4*>(&W[(2 * kp) * FD + 4 * q]);
            const f32x4 w1 = *reinterpret_cast<const f32x4*>(&W[(2 * kp + 1) * FD + 4 * q]);
            #pragma unroll
            for (int e2 = 0; e2 < 4; ++e2) {
                const unsigned int pk = (unsigned int)f2bf(w0[e2])
                                      | ((unsigned int)f2bf(w1[e2]) << 16);
                *reinterpret_cast<unsigned int*>(&Wt[(4 * q + e2) * LDS_WK + 2 * kp]) = pk;
            }
        }
    }

    // x rows global -> registers -> bf16 frags (B operand)
    const int lane = t & 63, wv = t >> 6;
    const int g = lane >> 4, mrow = lane & 15;
    const long long node = rowBase + wv * 16 + mrow;    // this lane's node
    short8v xfrag[4];
    {
        const float* xr = x + node * FD + 4 * g;
        #pragma unroll
        for (int kb = 0; kb < 4; ++kb) {
            const f32x4 x0 = __builtin_nontemporal_load(
                reinterpret_cast<const f32x4*>(xr + 32 * kb));
            const f32x4 x1 = __builtin_nontemporal_load(
                reinterpret_cast<const f32x4*>(xr + 32 * kb + 16));
            short8v f;
            f[0] = (short)f2bf(x0[0]); f[1] = (short)f2bf(x0[1]);
            f[2] = (short)f2bf(x0[2]); f[3] = (short)f2bf(x0[3]);
            f[4] = (short)f2bf(x1[0]); f[5] = (short)f2bf(x1[1]);
            f[6] = (short)f2bf(x1[2]); f[7] = (short)f2bf(x1[3]);
            xfrag[kb] = f;
        }
    }
    __syncthreads();

    // MFMA main: 8 n-tiles x 4 k-steps, D = Wt-tile * x-tile (transposed product)
    float4v acc[8];
    #pragma unroll
    for (int tn = 0; tn < 8; ++tn) { acc[tn][0] = 0.f; acc[tn][1] = 0.f; acc[tn][2] = 0.f; acc[tn][3] = 0.f; }

    #pragma unroll
    for (int tn = 0; tn < 8; ++tn) {
        const int nbase = (16 * tn + mrow) * LDS_WK + 4 * g;
        #pragma unroll
        for (int kb = 0; kb < 4; ++kb) {
            const short4v lo = *reinterpret_cast<const short4v*>(&Wt[nbase + 32 * kb]);
            const short4v hi = *reinterpret_cast<const short4v*>(&Wt[nbase + 32 * kb + 16]);
            short8v wf;
            wf[0] = lo[0]; wf[1] = lo[1]; wf[2] = lo[2]; wf[3] = lo[3];
            wf[4] = hi[0]; wf[5] = hi[1]; wf[6] = hi[2]; wf[7] = hi[3];
            acc[tn] = __builtin_amdgcn_mfma_f32_16x16x32_bf16(wf, xfrag[kb], acc[tn], 0, 0, 0);
        }
    }

    // epilogue: lane owns node `node`, h cols 16tn+4g+0..3 per tn
    float s1p = 0.f, s2p = 0.f;
    #pragma unroll
    for (int tn = 0; tn < 8; ++tn) {
        const int col = 16 * tn + 4 * g;
        const unsigned int u0 = (unsigned int)f2bf(acc[tn][0])
                              | ((unsigned int)f2bf(acc[tn][1]) << 16);
        const unsigned int u1 = (unsigned int)f2bf(acc[tn][2])
                              | ((unsigned int)f2bf(acc[tn][3]) << 16);
        *reinterpret_cast<uint2*>(&hb[node * FD + col]) = make_uint2(u0, u1);
        const f32x4 a1 = *reinterpret_cast<const f32x4*>(&avec[col]);
        const f32x4 a2 = *reinterpret_cast<const f32x4*>(&avec[FD + col]);
        #pragma unroll
        for (int r = 0; r < 4; ++r) {
            s1p = fmaf(acc[tn][r], a1[r], s1p);
            s2p = fmaf(acc[tn][r], a2[r], s2p);
        }
    }
    s1p += __shfl_xor(s1p, 16, 64);  s2p += __shfl_xor(s2p, 16, 64);
    s1p += __shfl_xor(s1p, 32, 64);  s2p += __shfl_xor(s2p, 32, 64);
    if (lane < 16)
        s12[rowBase + wv * 16 + lane] = make_float2(s1p, s2p);
}

// Kernel B v2: 4 consecutive nodes per wave. ONE coalesced 64-lane adj load
// covers all 4 nodes; lane = 16j+d handles edge (node j, neighbor d) for the
// fully lane-parallel e/softmax phase (one 8-B s12 gather + one exp per lane,
// 4 shfl_xor). Neighbor indices AND attn weights distributed via v_readlane
// (VALU) -> 4 independent gather chains per wave (4x MLP, no scalar-load stalls).
__global__ __launch_bounds__(256) void gat_aggr(
    const int* __restrict__ adj, const unsigned short* __restrict__ hb,
    const float2* __restrict__ s12, float* __restrict__ out)
{
    const int t = threadIdx.x;
    const int lane = t & 63;
    const int wv_u = __builtin_amdgcn_readfirstlane(t) >> 6;  // uniform wave id
    const int bid = blockIdx.x;
    const int xcd = bid & 7, blk = bid >> 3;    // 2048 blocks: blk = 0..255
    const int bBase = xcd * SEQ;                // batch == XCD
    const int nodeLoc0 = blk * 16 + wv_u * 4;   // batch-local first node of wave

    // one coalesced 256-B load: adj rows of 4 consecutive nodes
    const int a_l = adj[((long long)(bBase + nodeLoc0)) * DEG + lane];

    // lane-parallel e: lane = 16j+d. s2 of neighbor 0 comes from lane 16j.
    const float2 sv = s12[bBase + a_l];                 // 8-B gather
    const float s2n0 = __shfl(sv.y, lane & 48, 64);
    float ev = sv.x + s2n0;
    ev = ev > 0.f ? ev : ALPHA * ev;
    float p = __expf(ev);          // no max-sub: |e| small, fp32 safe (validated)
    float sum = p;
    #pragma unroll
    for (int mo = 1; mo < 16; mo <<= 1) sum += __shfl_xor(sum, mo, 64);
    p *= 1.f / sum;                // lane 16j+d holds normalized attn p_{j,d}

    // gather-aggregate: 4 independent node chains, indices/weights via readlane
    #pragma unroll
    for (int j = 0; j < 4; ++j) {
        const long long node = (long long)bBase + nodeLoc0 + j;
        float a0 = 0.f, a1 = 0.f;
        #pragma unroll
        for (int d = 0; d < 16; ++d) {
            const int nbjd = __builtin_amdgcn_readlane(a_l, 16 * j + d);   // SGPR
            const float pd = __uint_as_float(
                __builtin_amdgcn_readlane(__float_as_uint(p), 16 * j + d));
            const unsigned int* rp = reinterpret_cast<const unsigned int*>(
                hb + (((long long)(bBase + nbjd)) << 7));
            const unsigned int u = rp[lane];    // one 256-B row per instruction
            a0 = fmaf(pd, __uint_as_float(u << 16), a0);
            a1 = fmaf(pd, __uint_as_float(u & 0xffff0000u), a1);
        }
        f32x2 o;
        o[0] = a0 > 0.f ? a0 : (__expf(a0) - 1.f);
        o[1] = a1 > 0.f ? a1 : (__expf(a1) - 1.f);
        __builtin_nontemporal_store(o, reinterpret_cast<f32x2*>(
            out + node * FD + lane * 2));
    }
}

extern "C" void kernel_launch(void* const* d_in, const int* in_sizes, int n_in,
                              void* d_out, int out_size, void* d_ws, size_t ws_size,
                              hipStream_t stream) {
    const float* x  = (const float*)d_in[0];
    const int* adj  = (const int*)d_in[1];
    const float* W  = (const float*)d_in[2];
    const float* a  = (const float*)d_in[3];
    float* out = (float*)d_out;

    unsigned short* hb = (unsigned short*)d_ws;                          // 8 MB bf16 h
    float2* s12 = (float2*)((char*)d_ws + (size_t)NTOT * FD * 2);        // 256 KB scores

    gat_proj<<<dim3(NTOT / 64), dim3(256), 0, stream>>>(x, W, a, hb, s12);
    gat_aggr<<<dim3(NTOT / 16), dim3(256), 0, stream>>>(adj, hb, s12, out);
}